// Round 10
// baseline (267.854 us; speedup 1.0000x reference)
//
#include <hip/hip_runtime.h>
#include <hip/hip_bf16.h>
#include <stdint.h>

typedef __attribute__((ext_vector_type(8))) short short8;
typedef __attribute__((ext_vector_type(4))) float floatx4;

#define FEAT_DIM 1536
#define QD 64
#define NROWS 8192
#define TT 513

__device__ __forceinline__ unsigned short f2bf(float x) {
  union { float f; unsigned u; } t; t.f = x;
  unsigned r = t.u + 0x7fffu + ((t.u >> 16) & 1u);
  return (unsigned short)(r >> 16);
}
__device__ __forceinline__ float bf2f(unsigned short u) {
  union { float f; unsigned u; } t; t.u = ((unsigned)u) << 16;
  return t.f;
}
// monotone float->uint map (order-preserving), low 4 bits freed for an index
__device__ __forceinline__ unsigned packkey(float f, int idx) {
  unsigned x = __float_as_uint(f);
  unsigned m = (unsigned)((int)x >> 31);
  unsigned u = x ^ (m | 0x80000000u);
  return (u & ~15u) | (unsigned)idx;
}
__device__ __forceinline__ float unpackkey(unsigned u) {
  u &= ~15u;
  unsigned x = (u & 0x80000000u) ? (u ^ 0x80000000u) : ~u;
  return __uint_as_float(x);
}

// K0: R4-exact prep (proj -> bf16 MFMA B-fragment order). R9's A/B proved the
// last-arrival k_mf costs ~+31us vs plain merge+final launches, so fcnt and
// all device-side sync are gone; back to the 150.2us six-launch skeleton.
__global__ __launch_bounds__(256) void k_prep(const float* __restrict__ proj,
                                              unsigned short* __restrict__ prepB) {
  int t = blockIdx.x * 256 + threadIdx.x;   // 0..12287
  int q = t & 3, nn = (t >> 2) & 15, sub = (t >> 6) & 3, c = t >> 8;
  const float* src = proj + (size_t)(c * 32 + q * 8) * QD + sub * 16 + nn;
  union { unsigned short u[8]; short8 v; } P;
#pragma unroll
  for (int j = 0; j < 8; ++j) P.u[j] = f2bf(src[j * QD]);
  *(short8*)(prepB + (size_t)t * 8) = P.v;
}

// K1a: byte-identical R4/R9 k_sfs (prepB B-frags, LDS-staged feat tile,
// split-K 2048 blocks, plain float4 sff32 stores).
__global__ __launch_bounds__(256, 4) void k_sfs(const float* __restrict__ feat,
                                                const unsigned short* __restrict__ prepB,
                                                float* __restrict__ sff32) {
  const int tid = threadIdx.x;
  const int wave = tid >> 6, lane = tid & 63;
  const int q = lane >> 4, n = lane & 15;
  const int rowblk = blockIdx.x >> 2, kp = blockIdx.x & 3;
  const int rbase = rowblk * 16;
  const int b = rbase >> 9, ti0 = rbase & 511;   // 16-row blocks never cross b (512%16==0)
  const float* fb0 = feat + (size_t)(b * TT + ti0) * FEAT_DIM;
  const int k0 = kp * 384;

  __shared__ float lds[17 * 384];                // 26112 B (epilogue overlays it)

  // ---- stage: 1632 16B slots over 256 threads = 6 full rounds + 96-thread tail
  floatx4 sv[7];
  int dstw[7];
#pragma unroll
  for (int ri = 0; ri < 7; ++ri) {
    const int slot = ri * 256 + tid;
    const bool ok = (ri < 6) || (tid < 96);
    const int w = slot * 4;
    const int row = w / 384;                     // 0..16
    const int kk = w - row * 384;
    dstw[ri] = row * 384 + (kk ^ ((row & 7) << 2));
    if (ok) sv[ri] = *(const floatx4*)(fb0 + row * FEAT_DIM + k0 + kk);
  }

  // ---- B-fragments for this wave's 3 chunks: issue while staging is in flight
  const short8* pb = (const short8*)prepB + ((size_t)(k0 + wave * 96) >> 5) * 256 + n * 4 + q;
  short8 Bv0[4], Bv1[4], Bv2[4];
#pragma unroll
  for (int c = 0; c < 4; ++c) {
    Bv0[c] = pb[c * 64];
    Bv1[c] = pb[256 + c * 64];
    Bv2[c] = pb[512 + c * 64];
  }

#pragma unroll
  for (int ri = 0; ri < 7; ++ri)
    if ((ri < 6) || (tid < 96)) *(floatx4*)&lds[dstw[ri]] = sv[ri];
  __syncthreads();

  // ---- compute: wave w owns K-sub [w*96, w*96+96) of this 384 quarter
  floatx4 acc0 = {0,0,0,0}, acc1 = {0,0,0,0}, acc2 = {0,0,0,0}, acc3 = {0,0,0,0};
  const int swf = (n & 7) << 2, swg = ((n + 1) & 7) << 2;
  const int rowf = n * 384, rowg = (n + 1) * 384;
#pragma unroll
  for (int ks = 0; ks < 3; ++ks) {
    const int kb = wave * 96 + ks * 32 + q * 8;
    floatx4 f0 = *(const floatx4*)&lds[rowf + (kb ^ swf)];
    floatx4 f1 = *(const floatx4*)&lds[rowf + ((kb + 4) ^ swf)];
    floatx4 g0 = *(const floatx4*)&lds[rowg + (kb ^ swg)];
    floatx4 g1 = *(const floatx4*)&lds[rowg + ((kb + 4) ^ swg)];
    union { unsigned short u[8]; short8 v; } A;
#pragma unroll
    for (int j = 0; j < 4; ++j) A.u[j] = f2bf(0.5f * (f0[j] + g0[j]));
#pragma unroll
    for (int j = 0; j < 4; ++j) A.u[4 + j] = f2bf(0.5f * (f1[j] + g1[j]));
    const short8* Bc = (ks == 0) ? Bv0 : (ks == 1) ? Bv1 : Bv2;
    acc0 = __builtin_amdgcn_mfma_f32_16x16x32_bf16(A.v, Bc[0], acc0, 0, 0, 0);
    acc1 = __builtin_amdgcn_mfma_f32_16x16x32_bf16(A.v, Bc[1], acc1, 0, 0, 0);
    acc2 = __builtin_amdgcn_mfma_f32_16x16x32_bf16(A.v, Bc[2], acc2, 0, 0, 0);
    acc3 = __builtin_amdgcn_mfma_f32_16x16x32_bf16(A.v, Bc[3], acc3, 0, 0, 0);
  }

  __syncthreads();                               // staged data dead -> overlay as part[]
  float (*part)[16][64] = (float (*)[16][64])lds;
#pragma unroll
  for (int r = 0; r < 4; ++r) {
    part[wave][q * 4 + r][0 * 16 + n] = acc0[r];
    part[wave][q * 4 + r][1 * 16 + n] = acc1[r];
    part[wave][q * 4 + r][2 * 16 + n] = acc2[r];
    part[wave][q * 4 + r][3 * 16 + n] = acc3[r];
  }
  __syncthreads();
  {
    const int r = tid >> 4;
    const int c0 = (tid & 15) * 4;
    floatx4 o;
#pragma unroll
    for (int j = 0; j < 4; ++j)
      o[j] = ((part[0][r][c0 + j] + part[1][r][c0 + j]) +
               part[2][r][c0 + j]) + part[3][r][c0 + j];
    *(floatx4*)(sff32 + ((size_t)kp * NROWS + rbase + r) * QD + c0) = o;
  }
}

// K1b: byte-identical R4 k_sf_fin (sum 4 K-partials ascending, f2bf, sq).
__global__ __launch_bounds__(256) void k_sf_fin(const float* __restrict__ sff32,
                                                unsigned short* __restrict__ sfb,
                                                float* __restrict__ sq) {
  const int tid = threadIdx.x;
  const int rbase = blockIdx.x * 16;
  const int r = tid >> 4, c0 = (tid & 15) * 4;
  const size_t e = ((size_t)rbase + r) * QD + c0;
  floatx4 v0 = *(const floatx4*)(sff32 + e);
  floatx4 v1 = *(const floatx4*)(sff32 + (size_t)NROWS * QD + e);
  floatx4 v2 = *(const floatx4*)(sff32 + 2 * (size_t)NROWS * QD + e);
  floatx4 v3 = *(const floatx4*)(sff32 + 3 * (size_t)NROWS * QD + e);
  float sqp = 0.0f;
  union { unsigned short u[4]; uint2 d; } P;
#pragma unroll
  for (int j = 0; j < 4; ++j) {
    float v = ((v0[j] + v1[j]) + v2[j]) + v3[j];
    P.u[j] = f2bf(v);
    float bv = bf2f(P.u[j]);
    sqp += bv * bv;
  }
  *(uint2*)(sfb + e) = P.d;
#pragma unroll
  for (int off = 1; off < 16; off <<= 1) sqp += __shfl_xor(sqp, off, 64);
  if ((tid & 15) == 0) sq[rbase + r] = sqp;
}

// K2 v2: occupancy 2x with per-wave ILP UNCHANGED (R1's confound removed):
// same 32-row blocks + dual 16-deep insertion lists per lane (identical
// per-iteration body), but j split 8-ways (grid 2048, 256 j/wave, 16 iters)
// and the shfl-merge done in TWO passes over one half-size lists buffer:
// LDS 35.3KB -> 17.6KB. launch_bounds(256,8) (body uses 52 VGPR <= 64 cap)
// => 8 blocks/CU, 32 waves/CU resident vs 16.
__global__ __launch_bounds__(256, 8) void k_knn(const unsigned short* __restrict__ sfb,
                                                const float* __restrict__ sq,
                                                float* __restrict__ tops) {
  const int tid = threadIdx.x;
  const int wave = tid >> 6, lane = tid & 63;
  const int q = lane >> 4, n = lane & 15;
  const int ib = (blockIdx.x >> 3) * 32;
  const int js = blockIdx.x & 7;
  const short8* sfv = (const short8*)sfb;

  short8 b0 = sfv[(ib + n) * 8 + q];
  short8 b1 = sfv[(ib + n) * 8 + 4 + q];
  short8 b2 = sfv[(ib + 16 + n) * 8 + q];
  short8 b3 = sfv[(ib + 16 + n) * 8 + 4 + q];

  float lst0[16], lst1[16];
#pragma unroll
  for (int k = 0; k < 16; ++k) { lst0[k] = 3.0e38f; lst1[k] = 3.0e38f; }

  const int j0 = js * 1024 + wave * 256;
  short8 A0 = sfv[(j0 + n) * 8 + q];
  short8 A1 = sfv[(j0 + n) * 8 + 4 + q];
  floatx4 s4 = *(const floatx4*)(sq + j0 + q * 4);

#pragma unroll 2
  for (int jt = 0; jt < 256; jt += 16) {
    const int jn = j0 + jt + 16;   // final prefetch overruns into sq scratch: harmless
    short8 nA0 = sfv[(jn + n) * 8 + q];
    short8 nA1 = sfv[(jn + n) * 8 + 4 + q];
    floatx4 ns4 = *(const floatx4*)(sq + jn + q * 4);
    __builtin_amdgcn_sched_barrier(0);

    floatx4 acc0 = {0, 0, 0, 0};
    acc0 = __builtin_amdgcn_mfma_f32_16x16x32_bf16(A0, b0, acc0, 0, 0, 0);
    acc0 = __builtin_amdgcn_mfma_f32_16x16x32_bf16(A1, b1, acc0, 0, 0, 0);
    floatx4 acc1 = {0, 0, 0, 0};
    acc1 = __builtin_amdgcn_mfma_f32_16x16x32_bf16(A0, b2, acc1, 0, 0, 0);
    acc1 = __builtin_amdgcn_mfma_f32_16x16x32_bf16(A1, b3, acc1, 0, 0, 0);

#pragma unroll
    for (int r = 0; r < 4; ++r) {
      float c = fmaf(-2.0f, acc0[r], s4[r]);   // key = sq_j - 2*dot
#pragma unroll
      for (int k = 15; k >= 1; --k)
        lst0[k] = __builtin_amdgcn_fmed3f(lst0[k], lst0[k - 1], c);
      lst0[0] = fminf(lst0[0], c);
    }
#pragma unroll
    for (int r = 0; r < 4; ++r) {
      float c = fmaf(-2.0f, acc1[r], s4[r]);
#pragma unroll
      for (int k = 15; k >= 1; --k)
        lst1[k] = __builtin_amdgcn_fmed3f(lst1[k], lst1[k - 1], c);
      lst1[0] = fminf(lst1[0], c);
    }
    A0 = nA0; A1 = nA1; s4 = ns4;
  }

  // two-pass merge in a half-size buffer (16 rows per pass)
  __shared__ unsigned lists[16 * 275];
  const int sl = wave * 4 + q;
  const int sub = lane & 15;
  const int rr = wave * 4 + (lane >> 4);       // 0..15

  // ---- pass 0: rows ib..ib+15 (lst0)
#pragma unroll
  for (int k = 0; k < 16; ++k)
    lists[sl * 275 + n * 17 + k] = packkey(lst0[k], sl);
  __syncthreads();
  {
    int p = 0;
    unsigned h = lists[sub * 275 + rr * 17];
    float* trow = tops + ((size_t)(ib + rr) * 8 + js) * 16;
#pragma unroll 1
    for (int it = 0; it < 16; ++it) {
      unsigned u = h;
#pragma unroll
      for (int off = 1; off < 16; off <<= 1) {
        unsigned u2 = __shfl_xor(u, off, 64);
        u = (u2 < u) ? u2 : u;
      }
      if (sub == 0) trow[it] = unpackkey(u);
      if ((u & 15u) == (unsigned)sub) { ++p; h = lists[sub * 275 + rr * 17 + p]; }
    }
  }
  __syncthreads();

  // ---- pass 1: rows ib+16..ib+31 (lst1)
#pragma unroll
  for (int k = 0; k < 16; ++k)
    lists[sl * 275 + n * 17 + k] = packkey(lst1[k], sl);
  __syncthreads();
  {
    int p = 0;
    unsigned h = lists[sub * 275 + rr * 17];
    float* trow = tops + ((size_t)(ib + 16 + rr) * 8 + js) * 16;
#pragma unroll 1
    for (int it = 0; it < 16; ++it) {
      unsigned u = h;
#pragma unroll
      for (int off = 1; off < 16; off <<= 1) {
        unsigned u2 = __shfl_xor(u, off, 64);
        u = (u2 < u) ? u2 : u;
      }
      if (sub == 0) trow[it] = unpackkey(u);
      if ((u & 15u) == (unsigned)sub) { ++p; h = lists[sub * 275 + rr * 17 + p]; }
    }
  }
}

// K2b: merge v2 -- 8 sorted runs of 16 per row (tops now [8192][8][16]).
// Same proven else-if head-update logic, widened to 8 heads.
__global__ __launch_bounds__(256) void k_merge(const float* __restrict__ tops,
                                               const float* __restrict__ sq,
                                               float* __restrict__ intrew,
                                               float* __restrict__ psum) {
  const int tid = threadIdx.x;
  __shared__ float buf[32][136];               // 128 + 8 pad
  const int ib = blockIdx.x * 32;
  const floatx4* tv = (const floatx4*)(tops + (size_t)ib * 128);
#pragma unroll
  for (int k = 0; k < 4; ++k) {
    int f4 = k * 256 + tid;                    // 0..1023 (32 rows x 32 float4)
    floatx4 v = tv[f4];
    int r = f4 >> 5, c = (f4 & 31) * 4;
    *(floatx4*)(&buf[r][c]) = v;
  }
  __syncthreads();
  __shared__ float rsum[1];
  if (tid < 32) {
    const float* bb = buf[tid];
    const int row = ib + tid;
    const float sqr = sq[row];
    float h0 = bb[0],  h1 = bb[16], h2 = bb[32], h3 = bb[48];
    float h4 = bb[64], h5 = bb[80], h6 = bb[96], h7 = bb[112];
    int c0 = 1, c1 = 17, c2 = 33, c3 = 49, c4 = 65, c5 = 81, c6 = 97, c7 = 113;
    float sum = 0.0f;
#pragma unroll 1
    for (int it = 0; it < 16; ++it) {
      float mA = fminf(fminf(h0, h1), fminf(h2, h3));
      float mB = fminf(fminf(h4, h5), fminf(h6, h7));
      float m = fminf(mA, mB);
      sum += sqrtf(fmaxf(sqr + m, 1e-12f));
      if (m == h0)      { h0 = (c0 < 16)  ? bb[c0] : 3.0e38f; ++c0; }
      else if (m == h1) { h1 = (c1 < 32)  ? bb[c1] : 3.0e38f; ++c1; }
      else if (m == h2) { h2 = (c2 < 48)  ? bb[c2] : 3.0e38f; ++c2; }
      else if (m == h3) { h3 = (c3 < 64)  ? bb[c3] : 3.0e38f; ++c3; }
      else if (m == h4) { h4 = (c4 < 80)  ? bb[c4] : 3.0e38f; ++c4; }
      else if (m == h5) { h5 = (c5 < 96)  ? bb[c5] : 3.0e38f; ++c5; }
      else if (m == h6) { h6 = (c6 < 112) ? bb[c6] : 3.0e38f; ++c6; }
      else              { h7 = (c7 < 128) ? bb[c7] : 3.0e38f; ++c7; }
    }
    float ir = sum * (1.0f / 16.0f);
    intrew[row] = ir;
    float w = ir;
#pragma unroll
    for (int off = 1; off < 32; off <<= 1) w += __shfl_xor(w, off, 64);
    if (tid == 0) rsum[0] = w;
  }
  __syncthreads();
  if (tid == 0) psum[blockIdx.x] = rsum[0];
}

// K3: byte-identical R4 k_final (StreamNorm + add reward).
__global__ __launch_bounds__(256) void k_final(const float* __restrict__ reward,
                                               const float* __restrict__ intrew,
                                               const float* __restrict__ psum,
                                               float* __restrict__ out) {
  const int tid = threadIdx.x;
  const int wave = tid >> 6, lane = tid & 63;
  float v = psum[tid];                       // 256 entries
#pragma unroll
  for (int off = 1; off < 64; off <<= 1) v += __shfl_xor(v, off, 64);
  __shared__ float ws4[4];
  if (lane == 0) ws4[wave] = v;
  __syncthreads();
  float total = ws4[0] + ws4[1] + ws4[2] + ws4[3];
  float mean = total * (1.0f / 8192.0f);
  float mag = 0.99f + 0.01f * mean;
  float inv = 1.0f / (mag + 1e-8f);
  int i = blockIdx.x * 256 + tid;            // 0..8191
  int b = i >> 9, ti = i & 511;
  out[i] = reward[b * TT + ti] + intrew[i] * inv;
}

extern "C" void kernel_launch(void* const* d_in, const int* in_sizes, int n_in,
                              void* d_out, int out_size, void* d_ws, size_t ws_size,
                              hipStream_t stream) {
  const float* feat   = (const float*)d_in[0];
  const float* reward = (const float*)d_in[1];
  const float* proj   = (const float*)d_in[2];
  float* out = (float*)d_out;

  char* ws = (char*)d_ws;
  unsigned short* sfb = (unsigned short*)ws;                   // 1 MB: sf bf16 [8192][64]
  float* sq           = (float*)(ws + 0x100000);               // 32 KB (64 KB reserved)
  float* intrew       = (float*)(ws + 0x110000);               // 32 KB
  float* psum         = (float*)(ws + 0x120000);               // 1 KB (256 floats)
  unsigned short* prepB = (unsigned short*)(ws + 0x130000);    // 192 KB: proj bf16 B-frags
  float* sff32        = (float*)(ws + 0x160000);               // 8 MB: [4][8192][64] f32 partials
  float* tops         = (float*)(ws + 0x960000);               // 4 MB: [8192][8][16]

  k_prep<<<48, 256, 0, stream>>>(proj, prepB);
  k_sfs<<<2048, 256, 0, stream>>>(feat, prepB, sff32);
  k_sf_fin<<<512, 256, 0, stream>>>(sff32, sfb, sq);
  k_knn<<<2048, 256, 0, stream>>>(sfb, sq, tops);
  k_merge<<<256, 256, 0, stream>>>(tops, sq, intrew, psum);
  k_final<<<32, 256, 0, stream>>>(reward, intrew, psum, out);
}

// Round 11
// 159.572 us; speedup vs baseline: 1.6786x; 1.6786x over previous
//
#include <hip/hip_runtime.h>
#include <hip/hip_bf16.h>
#include <stdint.h>

typedef __attribute__((ext_vector_type(8))) short short8;
typedef __attribute__((ext_vector_type(4))) float floatx4;

#define FEAT_DIM 1536
#define QD 64
#define NROWS 8192
#define TT 513

__device__ __forceinline__ unsigned short f2bf(float x) {
  union { float f; unsigned u; } t; t.f = x;
  unsigned r = t.u + 0x7fffu + ((t.u >> 16) & 1u);
  return (unsigned short)(r >> 16);
}
__device__ __forceinline__ float bf2f(unsigned short u) {
  union { float f; unsigned u; } t; t.u = ((unsigned)u) << 16;
  return t.f;
}
// monotone float->uint map (order-preserving), low 4 bits freed for an index
__device__ __forceinline__ unsigned packkey(float f, int idx) {
  unsigned x = __float_as_uint(f);
  unsigned m = (unsigned)((int)x >> 31);
  unsigned u = x ^ (m | 0x80000000u);
  return (u & ~15u) | (unsigned)idx;
}
__device__ __forceinline__ float unpackkey(unsigned u) {
  u &= ~15u;
  unsigned x = (u & 0x80000000u) ? (u ^ 0x80000000u) : ~u;
  return __uint_as_float(x);
}

// K0: R4-exact prep (proj -> bf16 MFMA B-fragment order).
__global__ __launch_bounds__(256) void k_prep(const float* __restrict__ proj,
                                              unsigned short* __restrict__ prepB) {
  int t = blockIdx.x * 256 + threadIdx.x;   // 0..12287
  int q = t & 3, nn = (t >> 2) & 15, sub = (t >> 6) & 3, c = t >> 8;
  const float* src = proj + (size_t)(c * 32 + q * 8) * QD + sub * 16 + nn;
  union { unsigned short u[8]; short8 v; } P;
#pragma unroll
  for (int j = 0; j < 8; ++j) P.u[j] = f2bf(src[j * QD]);
  *(short8*)(prepB + (size_t)t * 8) = P.v;
}

// K1a: byte-identical R4/R9 k_sfs (prepB B-frags, LDS-staged feat tile,
// split-K 2048 blocks, plain float4 sff32 stores).
__global__ __launch_bounds__(256, 4) void k_sfs(const float* __restrict__ feat,
                                                const unsigned short* __restrict__ prepB,
                                                float* __restrict__ sff32) {
  const int tid = threadIdx.x;
  const int wave = tid >> 6, lane = tid & 63;
  const int q = lane >> 4, n = lane & 15;
  const int rowblk = blockIdx.x >> 2, kp = blockIdx.x & 3;
  const int rbase = rowblk * 16;
  const int b = rbase >> 9, ti0 = rbase & 511;   // 16-row blocks never cross b (512%16==0)
  const float* fb0 = feat + (size_t)(b * TT + ti0) * FEAT_DIM;
  const int k0 = kp * 384;

  __shared__ float lds[17 * 384];                // 26112 B (epilogue overlays it)

  // ---- stage: 1632 16B slots over 256 threads = 6 full rounds + 96-thread tail
  floatx4 sv[7];
  int dstw[7];
#pragma unroll
  for (int ri = 0; ri < 7; ++ri) {
    const int slot = ri * 256 + tid;
    const bool ok = (ri < 6) || (tid < 96);
    const int w = slot * 4;
    const int row = w / 384;                     // 0..16
    const int kk = w - row * 384;
    dstw[ri] = row * 384 + (kk ^ ((row & 7) << 2));
    if (ok) sv[ri] = *(const floatx4*)(fb0 + row * FEAT_DIM + k0 + kk);
  }

  // ---- B-fragments for this wave's 3 chunks: issue while staging is in flight
  const short8* pb = (const short8*)prepB + ((size_t)(k0 + wave * 96) >> 5) * 256 + n * 4 + q;
  short8 Bv0[4], Bv1[4], Bv2[4];
#pragma unroll
  for (int c = 0; c < 4; ++c) {
    Bv0[c] = pb[c * 64];
    Bv1[c] = pb[256 + c * 64];
    Bv2[c] = pb[512 + c * 64];
  }

#pragma unroll
  for (int ri = 0; ri < 7; ++ri)
    if ((ri < 6) || (tid < 96)) *(floatx4*)&lds[dstw[ri]] = sv[ri];
  __syncthreads();

  // ---- compute: wave w owns K-sub [w*96, w*96+96) of this 384 quarter
  floatx4 acc0 = {0,0,0,0}, acc1 = {0,0,0,0}, acc2 = {0,0,0,0}, acc3 = {0,0,0,0};
  const int swf = (n & 7) << 2, swg = ((n + 1) & 7) << 2;
  const int rowf = n * 384, rowg = (n + 1) * 384;
#pragma unroll
  for (int ks = 0; ks < 3; ++ks) {
    const int kb = wave * 96 + ks * 32 + q * 8;
    floatx4 f0 = *(const floatx4*)&lds[rowf + (kb ^ swf)];
    floatx4 f1 = *(const floatx4*)&lds[rowf + ((kb + 4) ^ swf)];
    floatx4 g0 = *(const floatx4*)&lds[rowg + (kb ^ swg)];
    floatx4 g1 = *(const floatx4*)&lds[rowg + ((kb + 4) ^ swg)];
    union { unsigned short u[8]; short8 v; } A;
#pragma unroll
    for (int j = 0; j < 4; ++j) A.u[j] = f2bf(0.5f * (f0[j] + g0[j]));
#pragma unroll
    for (int j = 0; j < 4; ++j) A.u[4 + j] = f2bf(0.5f * (f1[j] + g1[j]));
    const short8* Bc = (ks == 0) ? Bv0 : (ks == 1) ? Bv1 : Bv2;
    acc0 = __builtin_amdgcn_mfma_f32_16x16x32_bf16(A.v, Bc[0], acc0, 0, 0, 0);
    acc1 = __builtin_amdgcn_mfma_f32_16x16x32_bf16(A.v, Bc[1], acc1, 0, 0, 0);
    acc2 = __builtin_amdgcn_mfma_f32_16x16x32_bf16(A.v, Bc[2], acc2, 0, 0, 0);
    acc3 = __builtin_amdgcn_mfma_f32_16x16x32_bf16(A.v, Bc[3], acc3, 0, 0, 0);
  }

  __syncthreads();                               // staged data dead -> overlay as part[]
  float (*part)[16][64] = (float (*)[16][64])lds;
#pragma unroll
  for (int r = 0; r < 4; ++r) {
    part[wave][q * 4 + r][0 * 16 + n] = acc0[r];
    part[wave][q * 4 + r][1 * 16 + n] = acc1[r];
    part[wave][q * 4 + r][2 * 16 + n] = acc2[r];
    part[wave][q * 4 + r][3 * 16 + n] = acc3[r];
  }
  __syncthreads();
  {
    const int r = tid >> 4;
    const int c0 = (tid & 15) * 4;
    floatx4 o;
#pragma unroll
    for (int j = 0; j < 4; ++j)
      o[j] = ((part[0][r][c0 + j] + part[1][r][c0 + j]) +
               part[2][r][c0 + j]) + part[3][r][c0 + j];
    *(floatx4*)(sff32 + ((size_t)kp * NROWS + rbase + r) * QD + c0) = o;
  }
}

// K1b: byte-identical R4 k_sf_fin (sum 4 K-partials ascending, f2bf, sq).
__global__ __launch_bounds__(256) void k_sf_fin(const float* __restrict__ sff32,
                                                unsigned short* __restrict__ sfb,
                                                float* __restrict__ sq) {
  const int tid = threadIdx.x;
  const int rbase = blockIdx.x * 16;
  const int r = tid >> 4, c0 = (tid & 15) * 4;
  const size_t e = ((size_t)rbase + r) * QD + c0;
  floatx4 v0 = *(const floatx4*)(sff32 + e);
  floatx4 v1 = *(const floatx4*)(sff32 + (size_t)NROWS * QD + e);
  floatx4 v2 = *(const floatx4*)(sff32 + 2 * (size_t)NROWS * QD + e);
  floatx4 v3 = *(const floatx4*)(sff32 + 3 * (size_t)NROWS * QD + e);
  float sqp = 0.0f;
  union { unsigned short u[4]; uint2 d; } P;
#pragma unroll
  for (int j = 0; j < 4; ++j) {
    float v = ((v0[j] + v1[j]) + v2[j]) + v3[j];
    P.u[j] = f2bf(v);
    float bv = bf2f(P.u[j]);
    sqp += bv * bv;
  }
  *(uint2*)(sfb + e) = P.d;
#pragma unroll
  for (int off = 1; off < 16; off <<= 1) sqp += __shfl_xor(sqp, off, 64);
  if ((tid & 15) == 0) sq[rbase + r] = sqp;
}

// K2: R10's correctness-proven two-pass j-split knn, ONE change: launch_bounds
// (256,8) -> (256,4). R10's (256,8) forced the allocator to 32 VGPR and
// spilled both insertion lists (570MB scratch traffic, 172us). At (256,4)
// this body compiles to ~52 VGPR (R4/R9-proven); occupancy is then capped by
// LDS: 160KB / 17.9KB = 8 blocks/CU = 32 waves/CU, 2x the R4 version, with
// per-wave ILP (dual lists) unchanged. RULE: never force occupancy via
// launch_bounds on a register-hot kernel -- shrink LDS and let HW grant it.
__global__ __launch_bounds__(256, 4) void k_knn(const unsigned short* __restrict__ sfb,
                                                const float* __restrict__ sq,
                                                float* __restrict__ tops) {
  const int tid = threadIdx.x;
  const int wave = tid >> 6, lane = tid & 63;
  const int q = lane >> 4, n = lane & 15;
  const int ib = (blockIdx.x >> 3) * 32;
  const int js = blockIdx.x & 7;
  const short8* sfv = (const short8*)sfb;

  short8 b0 = sfv[(ib + n) * 8 + q];
  short8 b1 = sfv[(ib + n) * 8 + 4 + q];
  short8 b2 = sfv[(ib + 16 + n) * 8 + q];
  short8 b3 = sfv[(ib + 16 + n) * 8 + 4 + q];

  float lst0[16], lst1[16];
#pragma unroll
  for (int k = 0; k < 16; ++k) { lst0[k] = 3.0e38f; lst1[k] = 3.0e38f; }

  const int j0 = js * 1024 + wave * 256;
  short8 A0 = sfv[(j0 + n) * 8 + q];
  short8 A1 = sfv[(j0 + n) * 8 + 4 + q];
  floatx4 s4 = *(const floatx4*)(sq + j0 + q * 4);

#pragma unroll 2
  for (int jt = 0; jt < 256; jt += 16) {
    const int jn = j0 + jt + 16;   // final prefetch overruns into ws scratch: harmless
    short8 nA0 = sfv[(jn + n) * 8 + q];
    short8 nA1 = sfv[(jn + n) * 8 + 4 + q];
    floatx4 ns4 = *(const floatx4*)(sq + jn + q * 4);
    __builtin_amdgcn_sched_barrier(0);

    floatx4 acc0 = {0, 0, 0, 0};
    acc0 = __builtin_amdgcn_mfma_f32_16x16x32_bf16(A0, b0, acc0, 0, 0, 0);
    acc0 = __builtin_amdgcn_mfma_f32_16x16x32_bf16(A1, b1, acc0, 0, 0, 0);
    floatx4 acc1 = {0, 0, 0, 0};
    acc1 = __builtin_amdgcn_mfma_f32_16x16x32_bf16(A0, b2, acc1, 0, 0, 0);
    acc1 = __builtin_amdgcn_mfma_f32_16x16x32_bf16(A1, b3, acc1, 0, 0, 0);

#pragma unroll
    for (int r = 0; r < 4; ++r) {
      float c = fmaf(-2.0f, acc0[r], s4[r]);   // key = sq_j - 2*dot
#pragma unroll
      for (int k = 15; k >= 1; --k)
        lst0[k] = __builtin_amdgcn_fmed3f(lst0[k], lst0[k - 1], c);
      lst0[0] = fminf(lst0[0], c);
    }
#pragma unroll
    for (int r = 0; r < 4; ++r) {
      float c = fmaf(-2.0f, acc1[r], s4[r]);
#pragma unroll
      for (int k = 15; k >= 1; --k)
        lst1[k] = __builtin_amdgcn_fmed3f(lst1[k], lst1[k - 1], c);
      lst1[0] = fminf(lst1[0], c);
    }
    A0 = nA0; A1 = nA1; s4 = ns4;
  }

  // two-pass merge in a half-size buffer (16 rows per pass)
  __shared__ unsigned lists[16 * 275];
  const int sl = wave * 4 + q;
  const int sub = lane & 15;
  const int rr = wave * 4 + (lane >> 4);       // 0..15

  // ---- pass 0: rows ib..ib+15 (lst0)
#pragma unroll
  for (int k = 0; k < 16; ++k)
    lists[sl * 275 + n * 17 + k] = packkey(lst0[k], sl);
  __syncthreads();
  {
    int p = 0;
    unsigned h = lists[sub * 275 + rr * 17];
    float* trow = tops + ((size_t)(ib + rr) * 8 + js) * 16;
#pragma unroll 1
    for (int it = 0; it < 16; ++it) {
      unsigned u = h;
#pragma unroll
      for (int off = 1; off < 16; off <<= 1) {
        unsigned u2 = __shfl_xor(u, off, 64);
        u = (u2 < u) ? u2 : u;
      }
      if (sub == 0) trow[it] = unpackkey(u);
      if ((u & 15u) == (unsigned)sub) { ++p; h = lists[sub * 275 + rr * 17 + p]; }
    }
  }
  __syncthreads();

  // ---- pass 1: rows ib+16..ib+31 (lst1)
#pragma unroll
  for (int k = 0; k < 16; ++k)
    lists[sl * 275 + n * 17 + k] = packkey(lst1[k], sl);
  __syncthreads();
  {
    int p = 0;
    unsigned h = lists[sub * 275 + rr * 17];
    float* trow = tops + ((size_t)(ib + 16 + rr) * 8 + js) * 16;
#pragma unroll 1
    for (int it = 0; it < 16; ++it) {
      unsigned u = h;
#pragma unroll
      for (int off = 1; off < 16; off <<= 1) {
        unsigned u2 = __shfl_xor(u, off, 64);
        u = (u2 < u) ? u2 : u;
      }
      if (sub == 0) trow[it] = unpackkey(u);
      if ((u & 15u) == (unsigned)sub) { ++p; h = lists[sub * 275 + rr * 17 + p]; }
    }
  }
}

// K2b: byte-identical R10 merge (8 sorted runs of 16 per row, tops [8192][8][16]).
__global__ __launch_bounds__(256) void k_merge(const float* __restrict__ tops,
                                               const float* __restrict__ sq,
                                               float* __restrict__ intrew,
                                               float* __restrict__ psum) {
  const int tid = threadIdx.x;
  __shared__ float buf[32][136];               // 128 + 8 pad
  const int ib = blockIdx.x * 32;
  const floatx4* tv = (const floatx4*)(tops + (size_t)ib * 128);
#pragma unroll
  for (int k = 0; k < 4; ++k) {
    int f4 = k * 256 + tid;                    // 0..1023 (32 rows x 32 float4)
    floatx4 v = tv[f4];
    int r = f4 >> 5, c = (f4 & 31) * 4;
    *(floatx4*)(&buf[r][c]) = v;
  }
  __syncthreads();
  __shared__ float rsum[1];
  if (tid < 32) {
    const float* bb = buf[tid];
    const int row = ib + tid;
    const float sqr = sq[row];
    float h0 = bb[0],  h1 = bb[16], h2 = bb[32], h3 = bb[48];
    float h4 = bb[64], h5 = bb[80], h6 = bb[96], h7 = bb[112];
    int c0 = 1, c1 = 17, c2 = 33, c3 = 49, c4 = 65, c5 = 81, c6 = 97, c7 = 113;
    float sum = 0.0f;
#pragma unroll 1
    for (int it = 0; it < 16; ++it) {
      float mA = fminf(fminf(h0, h1), fminf(h2, h3));
      float mB = fminf(fminf(h4, h5), fminf(h6, h7));
      float m = fminf(mA, mB);
      sum += sqrtf(fmaxf(sqr + m, 1e-12f));
      if (m == h0)      { h0 = (c0 < 16)  ? bb[c0] : 3.0e38f; ++c0; }
      else if (m == h1) { h1 = (c1 < 32)  ? bb[c1] : 3.0e38f; ++c1; }
      else if (m == h2) { h2 = (c2 < 48)  ? bb[c2] : 3.0e38f; ++c2; }
      else if (m == h3) { h3 = (c3 < 64)  ? bb[c3] : 3.0e38f; ++c3; }
      else if (m == h4) { h4 = (c4 < 80)  ? bb[c4] : 3.0e38f; ++c4; }
      else if (m == h5) { h5 = (c5 < 96)  ? bb[c5] : 3.0e38f; ++c5; }
      else if (m == h6) { h6 = (c6 < 112) ? bb[c6] : 3.0e38f; ++c6; }
      else              { h7 = (c7 < 128) ? bb[c7] : 3.0e38f; ++c7; }
    }
    float ir = sum * (1.0f / 16.0f);
    intrew[row] = ir;
    float w = ir;
#pragma unroll
    for (int off = 1; off < 32; off <<= 1) w += __shfl_xor(w, off, 64);
    if (tid == 0) rsum[0] = w;
  }
  __syncthreads();
  if (tid == 0) psum[blockIdx.x] = rsum[0];
}

// K3: byte-identical R4 k_final (StreamNorm + add reward).
__global__ __launch_bounds__(256) void k_final(const float* __restrict__ reward,
                                               const float* __restrict__ intrew,
                                               const float* __restrict__ psum,
                                               float* __restrict__ out) {
  const int tid = threadIdx.x;
  const int wave = tid >> 6, lane = tid & 63;
  float v = psum[tid];                       // 256 entries
#pragma unroll
  for (int off = 1; off < 64; off <<= 1) v += __shfl_xor(v, off, 64);
  __shared__ float ws4[4];
  if (lane == 0) ws4[wave] = v;
  __syncthreads();
  float total = ws4[0] + ws4[1] + ws4[2] + ws4[3];
  float mean = total * (1.0f / 8192.0f);
  float mag = 0.99f + 0.01f * mean;
  float inv = 1.0f / (mag + 1e-8f);
  int i = blockIdx.x * 256 + tid;            // 0..8191
  int b = i >> 9, ti = i & 511;
  out[i] = reward[b * TT + ti] + intrew[i] * inv;
}

extern "C" void kernel_launch(void* const* d_in, const int* in_sizes, int n_in,
                              void* d_out, int out_size, void* d_ws, size_t ws_size,
                              hipStream_t stream) {
  const float* feat   = (const float*)d_in[0];
  const float* reward = (const float*)d_in[1];
  const float* proj   = (const float*)d_in[2];
  float* out = (float*)d_out;

  char* ws = (char*)d_ws;
  unsigned short* sfb = (unsigned short*)ws;                   // 1 MB: sf bf16 [8192][64]
  float* sq           = (float*)(ws + 0x100000);               // 32 KB (64 KB reserved)
  float* intrew       = (float*)(ws + 0x110000);               // 32 KB
  float* psum         = (float*)(ws + 0x120000);               // 1 KB (256 floats)
  unsigned short* prepB = (unsigned short*)(ws + 0x130000);    // 192 KB: proj bf16 B-frags
  float* sff32        = (float*)(ws + 0x160000);               // 8 MB: [4][8192][64] f32 partials
  float* tops         = (float*)(ws + 0x960000);               // 4 MB: [8192][8][16]

  k_prep<<<48, 256, 0, stream>>>(proj, prepB);
  k_sfs<<<2048, 256, 0, stream>>>(feat, prepB, sff32);
  k_sf_fin<<<512, 256, 0, stream>>>(sff32, sfb, sq);
  k_knn<<<2048, 256, 0, stream>>>(sfb, sq, tops);
  k_merge<<<256, 256, 0, stream>>>(tops, sq, intrew, psum);
  k_final<<<32, 256, 0, stream>>>(reward, intrew, psum, out);
}

// Round 12
// 152.086 us; speedup vs baseline: 1.7612x; 1.0492x over previous
//
#include <hip/hip_runtime.h>
#include <hip/hip_bf16.h>
#include <stdint.h>

typedef __attribute__((ext_vector_type(8))) short short8;
typedef __attribute__((ext_vector_type(4))) float floatx4;

#define FEAT_DIM 1536
#define QD 64
#define NROWS 8192
#define TT 513

__device__ __forceinline__ unsigned short f2bf(float x) {
  union { float f; unsigned u; } t; t.f = x;
  unsigned r = t.u + 0x7fffu + ((t.u >> 16) & 1u);
  return (unsigned short)(r >> 16);
}
__device__ __forceinline__ float bf2f(unsigned short u) {
  union { float f; unsigned u; } t; t.u = ((unsigned)u) << 16;
  return t.f;
}
// monotone float->uint map (order-preserving), low 4 bits freed for an index
__device__ __forceinline__ unsigned packkey(float f, int idx) {
  unsigned x = __float_as_uint(f);
  unsigned m = (unsigned)((int)x >> 31);
  unsigned u = x ^ (m | 0x80000000u);
  return (u & ~15u) | (unsigned)idx;
}
__device__ __forceinline__ float unpackkey(unsigned u) {
  u &= ~15u;
  unsigned x = (u & 0x80000000u) ? (u ^ 0x80000000u) : ~u;
  return __uint_as_float(x);
}

// K0: R4-exact prep (proj -> bf16 MFMA B-fragment order).
__global__ __launch_bounds__(256) void k_prep(const float* __restrict__ proj,
                                              unsigned short* __restrict__ prepB) {
  int t = blockIdx.x * 256 + threadIdx.x;   // 0..12287
  int q = t & 3, nn = (t >> 2) & 15, sub = (t >> 6) & 3, c = t >> 8;
  const float* src = proj + (size_t)(c * 32 + q * 8) * QD + sub * 16 + nn;
  union { unsigned short u[8]; short8 v; } P;
#pragma unroll
  for (int j = 0; j < 8; ++j) P.u[j] = f2bf(src[j * QD]);
  *(short8*)(prepB + (size_t)t * 8) = P.v;
}

// K1a: byte-identical R4/R9 k_sfs (prepB B-frags, LDS-staged feat tile,
// split-K 2048 blocks, plain float4 sff32 stores).
__global__ __launch_bounds__(256, 4) void k_sfs(const float* __restrict__ feat,
                                                const unsigned short* __restrict__ prepB,
                                                float* __restrict__ sff32) {
  const int tid = threadIdx.x;
  const int wave = tid >> 6, lane = tid & 63;
  const int q = lane >> 4, n = lane & 15;
  const int rowblk = blockIdx.x >> 2, kp = blockIdx.x & 3;
  const int rbase = rowblk * 16;
  const int b = rbase >> 9, ti0 = rbase & 511;   // 16-row blocks never cross b (512%16==0)
  const float* fb0 = feat + (size_t)(b * TT + ti0) * FEAT_DIM;
  const int k0 = kp * 384;

  __shared__ float lds[17 * 384];                // 26112 B (epilogue overlays it)

  // ---- stage: 1632 16B slots over 256 threads = 6 full rounds + 96-thread tail
  floatx4 sv[7];
  int dstw[7];
#pragma unroll
  for (int ri = 0; ri < 7; ++ri) {
    const int slot = ri * 256 + tid;
    const bool ok = (ri < 6) || (tid < 96);
    const int w = slot * 4;
    const int row = w / 384;                     // 0..16
    const int kk = w - row * 384;
    dstw[ri] = row * 384 + (kk ^ ((row & 7) << 2));
    if (ok) sv[ri] = *(const floatx4*)(fb0 + row * FEAT_DIM + k0 + kk);
  }

  // ---- B-fragments for this wave's 3 chunks: issue while staging is in flight
  const short8* pb = (const short8*)prepB + ((size_t)(k0 + wave * 96) >> 5) * 256 + n * 4 + q;
  short8 Bv0[4], Bv1[4], Bv2[4];
#pragma unroll
  for (int c = 0; c < 4; ++c) {
    Bv0[c] = pb[c * 64];
    Bv1[c] = pb[256 + c * 64];
    Bv2[c] = pb[512 + c * 64];
  }

#pragma unroll
  for (int ri = 0; ri < 7; ++ri)
    if ((ri < 6) || (tid < 96)) *(floatx4*)&lds[dstw[ri]] = sv[ri];
  __syncthreads();

  // ---- compute: wave w owns K-sub [w*96, w*96+96) of this 384 quarter
  floatx4 acc0 = {0,0,0,0}, acc1 = {0,0,0,0}, acc2 = {0,0,0,0}, acc3 = {0,0,0,0};
  const int swf = (n & 7) << 2, swg = ((n + 1) & 7) << 2;
  const int rowf = n * 384, rowg = (n + 1) * 384;
#pragma unroll
  for (int ks = 0; ks < 3; ++ks) {
    const int kb = wave * 96 + ks * 32 + q * 8;
    floatx4 f0 = *(const floatx4*)&lds[rowf + (kb ^ swf)];
    floatx4 f1 = *(const floatx4*)&lds[rowf + ((kb + 4) ^ swf)];
    floatx4 g0 = *(const floatx4*)&lds[rowg + (kb ^ swg)];
    floatx4 g1 = *(const floatx4*)&lds[rowg + ((kb + 4) ^ swg)];
    union { unsigned short u[8]; short8 v; } A;
#pragma unroll
    for (int j = 0; j < 4; ++j) A.u[j] = f2bf(0.5f * (f0[j] + g0[j]));
#pragma unroll
    for (int j = 0; j < 4; ++j) A.u[4 + j] = f2bf(0.5f * (f1[j] + g1[j]));
    const short8* Bc = (ks == 0) ? Bv0 : (ks == 1) ? Bv1 : Bv2;
    acc0 = __builtin_amdgcn_mfma_f32_16x16x32_bf16(A.v, Bc[0], acc0, 0, 0, 0);
    acc1 = __builtin_amdgcn_mfma_f32_16x16x32_bf16(A.v, Bc[1], acc1, 0, 0, 0);
    acc2 = __builtin_amdgcn_mfma_f32_16x16x32_bf16(A.v, Bc[2], acc2, 0, 0, 0);
    acc3 = __builtin_amdgcn_mfma_f32_16x16x32_bf16(A.v, Bc[3], acc3, 0, 0, 0);
  }

  __syncthreads();                               // staged data dead -> overlay as part[]
  float (*part)[16][64] = (float (*)[16][64])lds;
#pragma unroll
  for (int r = 0; r < 4; ++r) {
    part[wave][q * 4 + r][0 * 16 + n] = acc0[r];
    part[wave][q * 4 + r][1 * 16 + n] = acc1[r];
    part[wave][q * 4 + r][2 * 16 + n] = acc2[r];
    part[wave][q * 4 + r][3 * 16 + n] = acc3[r];
  }
  __syncthreads();
  {
    const int r = tid >> 4;
    const int c0 = (tid & 15) * 4;
    floatx4 o;
#pragma unroll
    for (int j = 0; j < 4; ++j)
      o[j] = ((part[0][r][c0 + j] + part[1][r][c0 + j]) +
               part[2][r][c0 + j]) + part[3][r][c0 + j];
    *(floatx4*)(sff32 + ((size_t)kp * NROWS + rbase + r) * QD + c0) = o;
  }
}

// K1b: byte-identical R4 k_sf_fin (sum 4 K-partials ascending, f2bf, sq).
__global__ __launch_bounds__(256) void k_sf_fin(const float* __restrict__ sff32,
                                                unsigned short* __restrict__ sfb,
                                                float* __restrict__ sq) {
  const int tid = threadIdx.x;
  const int rbase = blockIdx.x * 16;
  const int r = tid >> 4, c0 = (tid & 15) * 4;
  const size_t e = ((size_t)rbase + r) * QD + c0;
  floatx4 v0 = *(const floatx4*)(sff32 + e);
  floatx4 v1 = *(const floatx4*)(sff32 + (size_t)NROWS * QD + e);
  floatx4 v2 = *(const floatx4*)(sff32 + 2 * (size_t)NROWS * QD + e);
  floatx4 v3 = *(const floatx4*)(sff32 + 3 * (size_t)NROWS * QD + e);
  float sqp = 0.0f;
  union { unsigned short u[4]; uint2 d; } P;
#pragma unroll
  for (int j = 0; j < 4; ++j) {
    float v = ((v0[j] + v1[j]) + v2[j]) + v3[j];
    P.u[j] = f2bf(v);
    float bv = bf2f(P.u[j]);
    sqp += bv * bv;
  }
  *(uint2*)(sfb + e) = P.d;
#pragma unroll
  for (int off = 1; off < 16; off <<= 1) sqp += __shfl_xor(sqp, off, 64);
  if ((tid & 15) == 0) sq[rbase + r] = sqp;
}

// K2: R4's 55.6us knn structure (32-row blocks, 4-js split, dual lists,
// 1024 grid) with ONE change: EXPLICIT 2-deep prefetch. R11 proved the
// 40% stall is NOT occupancy (40% occ gave 0 gain); it is the 1-deep
// rotate-prefetch: ~150cy of compute between consume and next use vs
// ~300cy L2 latency. Two register buffer sets double the latency budget.
// Same j order -> bit-identical output. VGPR 52 -> ~64 (cap 128, no spill).
// Prefetch overrun now 32 rows past sfb (was 16): still lands in dead ws
// pad (sq tail / reserved gap), loaded-but-never-used.
__global__ __launch_bounds__(256, 4) void k_knn(const unsigned short* __restrict__ sfb,
                                                const float* __restrict__ sq,
                                                float* __restrict__ tops) {
  const int tid = threadIdx.x;
  const int wave = tid >> 6, lane = tid & 63;
  const int q = lane >> 4, n = lane & 15;
  const int ib = (blockIdx.x >> 2) * 32;
  const int js = blockIdx.x & 3;
  const short8* sfv = (const short8*)sfb;

  short8 b0 = sfv[(ib + n) * 8 + q];
  short8 b1 = sfv[(ib + n) * 8 + 4 + q];
  short8 b2 = sfv[(ib + 16 + n) * 8 + q];
  short8 b3 = sfv[(ib + 16 + n) * 8 + 4 + q];

  float lst0[16], lst1[16];
#pragma unroll
  for (int k = 0; k < 16; ++k) { lst0[k] = 3.0e38f; lst1[k] = 3.0e38f; }

  const int j0 = js * 2048 + wave * 512;
  // 2-deep prefetch: set a = jt, set b = jt+16
  short8 A0a = sfv[(j0 + n) * 8 + q];
  short8 A1a = sfv[(j0 + n) * 8 + 4 + q];
  floatx4 s4a = *(const floatx4*)(sq + j0 + q * 4);
  short8 A0b = sfv[(j0 + 16 + n) * 8 + q];
  short8 A1b = sfv[(j0 + 16 + n) * 8 + 4 + q];
  floatx4 s4b = *(const floatx4*)(sq + j0 + 16 + q * 4);

#pragma unroll 2
  for (int jt = 0; jt < 512; jt += 16) {
    const int jn = j0 + jt + 32;   // prefetch 2 tiles ahead (overrun harmless)
    short8 nA0 = sfv[(jn + n) * 8 + q];
    short8 nA1 = sfv[(jn + n) * 8 + 4 + q];
    floatx4 ns4 = *(const floatx4*)(sq + jn + q * 4);
    __builtin_amdgcn_sched_barrier(0);

    floatx4 acc0 = {0, 0, 0, 0};
    acc0 = __builtin_amdgcn_mfma_f32_16x16x32_bf16(A0a, b0, acc0, 0, 0, 0);
    acc0 = __builtin_amdgcn_mfma_f32_16x16x32_bf16(A1a, b1, acc0, 0, 0, 0);
    floatx4 acc1 = {0, 0, 0, 0};
    acc1 = __builtin_amdgcn_mfma_f32_16x16x32_bf16(A0a, b2, acc1, 0, 0, 0);
    acc1 = __builtin_amdgcn_mfma_f32_16x16x32_bf16(A1a, b3, acc1, 0, 0, 0);

#pragma unroll
    for (int r = 0; r < 4; ++r) {
      float c = fmaf(-2.0f, acc0[r], s4a[r]);   // key = sq_j - 2*dot
#pragma unroll
      for (int k = 15; k >= 1; --k)
        lst0[k] = __builtin_amdgcn_fmed3f(lst0[k], lst0[k - 1], c);
      lst0[0] = fminf(lst0[0], c);
    }
#pragma unroll
    for (int r = 0; r < 4; ++r) {
      float c = fmaf(-2.0f, acc1[r], s4a[r]);
#pragma unroll
      for (int k = 15; k >= 1; --k)
        lst1[k] = __builtin_amdgcn_fmed3f(lst1[k], lst1[k - 1], c);
      lst1[0] = fminf(lst1[0], c);
    }
    A0a = A0b; A1a = A1b; s4a = s4b;
    A0b = nA0; A1b = nA1; s4b = ns4;
  }

  __shared__ unsigned lists[16 * 547];
  const int sl = wave * 4 + q;
#pragma unroll
  for (int k = 0; k < 16; ++k) {
    lists[sl * 547 + n * 17 + k] = packkey(lst0[k], sl);
    lists[sl * 547 + (n + 16) * 17 + k] = packkey(lst1[k], sl);
  }
  __syncthreads();

  const int sub = lane & 15;
#pragma unroll 1
  for (int pass = 0; pass < 2; ++pass) {
    const int rr = pass * 16 + wave * 4 + (lane >> 4);   // 0..31
    int p = 0;
    unsigned h = lists[sub * 547 + rr * 17];
    float* trow = tops + ((size_t)(ib + rr) * 4 + js) * 16;
#pragma unroll 1
    for (int it = 0; it < 16; ++it) {
      unsigned u = h;
#pragma unroll
      for (int off = 1; off < 16; off <<= 1) {
        unsigned u2 = __shfl_xor(u, off, 64);
        u = (u2 < u) ? u2 : u;
      }
      if (sub == 0) trow[it] = unpackkey(u);
      if ((u & 15u) == (unsigned)sub) { ++p; h = lists[sub * 547 + rr * 17 + p]; }
    }
  }
}

// K2b: byte-identical R4 merge (tops [8192][4][16], 4 heads).
__global__ __launch_bounds__(256) void k_merge(const float* __restrict__ tops,
                                               const float* __restrict__ sq,
                                               float* __restrict__ intrew,
                                               float* __restrict__ psum) {
  const int tid = threadIdx.x;
  __shared__ float buf[32][68];
  const int ib = blockIdx.x * 32;
  const floatx4* tv = (const floatx4*)(tops + (size_t)ib * 64);
#pragma unroll
  for (int k = 0; k < 2; ++k) {
    int f4 = k * 256 + tid;                  // 0..511 (32 rows x 16 float4)
    floatx4 v = tv[f4];
    int r = f4 >> 4, c = (f4 & 15) * 4;
    *(floatx4*)(&buf[r][c]) = v;
  }
  __syncthreads();
  __shared__ float rsum[1];
  if (tid < 32) {
    const float* bb = buf[tid];
    const int row = ib + tid;
    const float sqr = sq[row];
    int c0 = 1, c1 = 17, c2 = 33, c3 = 49;
    float h0 = bb[0], h1 = bb[16], h2 = bb[32], h3 = bb[48];
    float sum = 0.0f;
#pragma unroll 1
    for (int it = 0; it < 16; ++it) {
      float m = fminf(fminf(h0, h1), fminf(h2, h3));
      sum += sqrtf(fmaxf(sqr + m, 1e-12f));
      if (m == h0)      { h0 = (c0 < 16) ? bb[c0] : 3.0e38f; ++c0; }
      else if (m == h1) { h1 = (c1 < 32) ? bb[c1] : 3.0e38f; ++c1; }
      else if (m == h2) { h2 = (c2 < 48) ? bb[c2] : 3.0e38f; ++c2; }
      else              { h3 = (c3 < 64) ? bb[c3] : 3.0e38f; ++c3; }
    }
    float ir = sum * (1.0f / 16.0f);
    intrew[row] = ir;
    float w = ir;
#pragma unroll
    for (int off = 1; off < 32; off <<= 1) w += __shfl_xor(w, off, 64);
    if (tid == 0) rsum[0] = w;
  }
  __syncthreads();
  if (tid == 0) psum[blockIdx.x] = rsum[0];
}

// K3: byte-identical R4 k_final (StreamNorm + add reward).
__global__ __launch_bounds__(256) void k_final(const float* __restrict__ reward,
                                               const float* __restrict__ intrew,
                                               const float* __restrict__ psum,
                                               float* __restrict__ out) {
  const int tid = threadIdx.x;
  const int wave = tid >> 6, lane = tid & 63;
  float v = psum[tid];                       // 256 entries
#pragma unroll
  for (int off = 1; off < 64; off <<= 1) v += __shfl_xor(v, off, 64);
  __shared__ float ws4[4];
  if (lane == 0) ws4[wave] = v;
  __syncthreads();
  float total = ws4[0] + ws4[1] + ws4[2] + ws4[3];
  float mean = total * (1.0f / 8192.0f);
  float mag = 0.99f + 0.01f * mean;
  float inv = 1.0f / (mag + 1e-8f);
  int i = blockIdx.x * 256 + tid;            // 0..8191
  int b = i >> 9, ti = i & 511;
  out[i] = reward[b * TT + ti] + intrew[i] * inv;
}

extern "C" void kernel_launch(void* const* d_in, const int* in_sizes, int n_in,
                              void* d_out, int out_size, void* d_ws, size_t ws_size,
                              hipStream_t stream) {
  const float* feat   = (const float*)d_in[0];
  const float* reward = (const float*)d_in[1];
  const float* proj   = (const float*)d_in[2];
  float* out = (float*)d_out;

  char* ws = (char*)d_ws;
  unsigned short* sfb = (unsigned short*)ws;                   // 1 MB: sf bf16 [8192][64]
  float* sq           = (float*)(ws + 0x100000);               // 32 KB
  float* intrew       = (float*)(ws + 0x110000);               // 32 KB
  float* psum         = (float*)(ws + 0x120000);               // 1 KB (256 floats)
  unsigned short* prepB = (unsigned short*)(ws + 0x130000);    // 192 KB: proj bf16 B-frags
  float* tops         = (float*)(ws + 0x160000);               // 2 MB: [8192][4][16]
  float* sff32        = (float*)(ws + 0x360000);               // 8 MB: [4][8192][64] f32 partials

  k_prep<<<48, 256, 0, stream>>>(proj, prepB);
  k_sfs<<<2048, 256, 0, stream>>>(feat, prepB, sff32);
  k_sf_fin<<<512, 256, 0, stream>>>(sff32, sfb, sq);
  k_knn<<<1024, 256, 0, stream>>>(sfb, sq, tops);
  k_merge<<<256, 256, 0, stream>>>(tops, sq, intrew, psum);
  k_final<<<32, 256, 0, stream>>>(reward, intrew, psum, out);
}